// Round 2
// baseline (77.263 us; speedup 1.0000x reference)
//
#include <hip/hip_runtime.h>
#include <hip/hip_bf16.h>

#define INF_VAL 100000000.0f
#define RADIUS 1.5f
#define NUM_CLASSES 80
#define G_BOXES 50

// One thread per (batch, location). Block = 256 locations, grid.y = batch.
// LDS stages the 50 boxes (+ precomputed cx, cy, area) and classes once per block.
// Output dtype: FLOAT32 (reference outputs are int32/float32 -> harness uses float*).
__global__ void __launch_bounds__(256) fcos_assign_kernel(
    const float* __restrict__ locations,    // [L,2]
    const float* __restrict__ stride_loc,   // [L]
    const float* __restrict__ size_ranges,  // [L,2]
    const float* __restrict__ gt_boxes,     // [B,G,4]
    const int*   __restrict__ gt_classes,   // [B,G]
    float* __restrict__ out,                // labels[B*L] ++ reg[B*L*4] ++ ctr[B*L]
    int L, int B)
{
    const int b = blockIdx.y;
    const int i = blockIdx.x * blockDim.x + threadIdx.x;

    // LDS: per-box x0,y0,x1,y1,cx,cy,area (7 floats) + class
    __shared__ float sbox[G_BOXES][7];
    __shared__ int   scls[G_BOXES];

    if (threadIdx.x < G_BOXES) {
        const int g = threadIdx.x;
        const float4 bx = *reinterpret_cast<const float4*>(gt_boxes + ((size_t)b * G_BOXES + g) * 4);
        sbox[g][0] = bx.x; sbox[g][1] = bx.y; sbox[g][2] = bx.z; sbox[g][3] = bx.w;
        sbox[g][4] = (bx.x + bx.z) * 0.5f;
        sbox[g][5] = (bx.y + bx.w) * 0.5f;
        sbox[g][6] = (bx.z - bx.x) * (bx.w - bx.y);
        scls[g] = gt_classes[(size_t)b * G_BOXES + g];
    }
    __syncthreads();

    if (i >= L) return;

    const float2 xy = *reinterpret_cast<const float2*>(locations + 2 * (size_t)i);
    const float x = xy.x, y = xy.y;
    const float stride = stride_loc[i];
    const float2 sr = *reinterpret_cast<const float2*>(size_ranges + 2 * (size_t)i);
    const float lo = sr.x, hi = sr.y;
    const float rad = stride * RADIUS;

    float best_area = INF_VAL;
    int best_g = 0;

    #pragma unroll 5
    for (int g = 0; g < G_BOXES; ++g) {
        const float bx0 = sbox[g][0], by0 = sbox[g][1];
        const float bx1 = sbox[g][2], by1 = sbox[g][3];
        const float cx  = sbox[g][4], cy  = sbox[g][5];
        const float area = sbox[g][6];

        const float l  = x - bx0;
        const float t  = y - by0;
        const float r  = bx1 - x;
        const float bt = by1 - y;

        // center-sampling box clipped to gt box
        const float x0 = fmaxf(cx - rad, bx0);
        const float y0 = fmaxf(cy - rad, by0);
        const float x1 = fminf(cx + rad, bx1);
        const float y1 = fminf(cy + rad, by1);
        const float cbm = fminf(fminf(x - x0, y - y0), fminf(x1 - x, y1 - y));
        const bool in_radius = cbm > 0.0f;

        const float max_reg = fminf(fmaxf(l, r), fmaxf(t, bt));
        const bool cared = (max_reg >= lo) && (max_reg <= hi);

        const float val = (in_radius && cared) ? area : INF_VAL;
        if (val < best_area) { best_area = val; best_g = g; }  // first-min tie-break == argmin
    }

    // reg of argmin box (argmin over all-INF row -> index 0, same as np/jnp argmin)
    const float bx0 = sbox[best_g][0], by0 = sbox[best_g][1];
    const float bx1 = sbox[best_g][2], by1 = sbox[best_g][3];
    const float inv_s = 1.0f / stride;  // strides are powers of two -> exact
    const float rl = (x - bx0) * inv_s;
    const float rt = (y - by0) * inv_s;
    const float rr = (bx1 - x) * inv_s;
    const float rb = (by1 - y) * inv_s;

    const float label = (best_area >= INF_VAL) ? (float)NUM_CLASSES : (float)scls[best_g];

    const float lr0 = rl + 1e-5f, lr1 = rr + 1e-5f;
    const float tb0 = rt + 1e-5f, tb1 = rb + 1e-5f;
    float ctr = (fminf(lr0, lr1) / fmaxf(lr0, lr1)) * (fminf(tb0, tb1) / fmaxf(tb0, tb1));
    ctr = sqrtf(fmaxf(ctr, 0.0f));

    const size_t BL = (size_t)B * L;
    const size_t bl = (size_t)b * L + i;

    out[bl] = label;

    // reg chunk: element offset BL + 4*bl; BL % 4 == 0 -> 16B-aligned float4 store
    float4 rg;
    rg.x = rl; rg.y = rt; rg.z = rr; rg.w = rb;
    *reinterpret_cast<float4*>(out + BL + bl * 4) = rg;

    out[5 * BL + bl] = ctr;
}

extern "C" void kernel_launch(void* const* d_in, const int* in_sizes, int n_in,
                              void* d_out, int out_size, void* d_ws, size_t ws_size,
                              hipStream_t stream) {
    const float* locations   = (const float*)d_in[0];
    const float* stride_loc  = (const float*)d_in[1];
    const float* size_ranges = (const float*)d_in[2];
    const float* gt_boxes    = (const float*)d_in[3];
    const int*   gt_classes  = (const int*)d_in[4];
    float* out = (float*)d_out;

    const int L = in_sizes[1];            // 20267
    const int B = in_sizes[4] / G_BOXES;  // 16

    dim3 block(256);
    dim3 grid((L + 255) / 256, B);
    fcos_assign_kernel<<<grid, block, 0, stream>>>(
        locations, stride_loc, size_ranges, gt_boxes, gt_classes, out, L, B);
}

// Round 4
// 75.239 us; speedup vs baseline: 1.0269x; 1.0269x over previous
//
#include <hip/hip_runtime.h>
#include <hip/hip_bf16.h>

#define INF_VAL 100000000.0f
#define RADIUS 1.5f
#define NUM_CLASSES 80
#define G_BOXES 50

// One thread per (batch, location). Block = 256 locations, grid.y = batch.
//
// Pipe balance (round-3 fix): the round-2 kernel was LDS-issue-bound
// (7x ds_read_b32 per box ~= 40 cyc/iter on the per-CU LDS pipe -> ~17us).
// Now: box coords come from UNIFORM global loads (s_load / L1 broadcast,
// off the LDS pipe); LDS holds one float4 {cx, cy, area, classf} per box
// -> 1x ds_read_b128 per iter.
//
// Exactness vs the numpy reference (threshold-critical, argmin tie-breaks):
//  - cx,cy,area precomputed with the reference's formulas -> identical bits.
//  - in_radius gate uses the exact equivalence
//      x - fmax(cx-rad, bx0) > 0  <=>  (x > cx-rad) && (x - bx0 > 0);
//    cx-rad computed directly (same rounding as ref), compares are exact.
//  - max_reg = fmin(fmax(l,r), fmax(t,bt)) identical; area compared as the
//    pre-rounded LDS value; strict < argmin keeps first-min tie-break.
//  - reg/stride done as mul by exact power-of-two reciprocal (bit-identical).
__global__ void __launch_bounds__(256) fcos_assign_kernel(
    const float* __restrict__ locations,    // [L,2]
    const float* __restrict__ stride_loc,   // [L]
    const float* __restrict__ size_ranges,  // [L,2]
    const float* __restrict__ gt_boxes,     // [B,G,4]
    const int*   __restrict__ gt_classes,   // [B,G]
    float* __restrict__ out,                // labels[B*L] ++ reg[B*L*4] ++ ctr[B*L]
    int L, int B)
{
    const int b = blockIdx.y;
    const int i = blockIdx.x * blockDim.x + threadIdx.x;

    // Derived per-box data: {cx, cy, area, class_as_float}
    __shared__ float4 sder[G_BOXES];

    const float4* __restrict__ box4 =
        reinterpret_cast<const float4*>(gt_boxes) + (size_t)b * G_BOXES;

    if (threadIdx.x < G_BOXES) {
        const int g = threadIdx.x;
        const float4 bx = box4[g];
        float4 v;
        v.x = (bx.x + bx.z) * 0.5f;            // cx  (ref rounding)
        v.y = (bx.y + bx.w) * 0.5f;            // cy
        v.z = (bx.z - bx.x) * (bx.w - bx.y);   // area
        v.w = (float)gt_classes[(size_t)b * G_BOXES + g];
        sder[g] = v;
    }
    __syncthreads();

    if (i >= L) return;

    const float2 xy = *reinterpret_cast<const float2*>(locations + 2 * (size_t)i);
    const float x = xy.x, y = xy.y;
    const float stride = stride_loc[i];
    const float2 sr = *reinterpret_cast<const float2*>(size_ranges + 2 * (size_t)i);
    const float lo = sr.x, hi = sr.y;
    const float rad = stride * RADIUS;

    float best_area = INF_VAL;
    int best_g = 0;

    #pragma unroll 5
    for (int g = 0; g < G_BOXES; ++g) {
        const float4 bx = box4[g];   // uniform address -> scalar/SMEM or L1 broadcast
        const float4 d  = sder[g];   // one ds_read_b128

        const float l  = x - bx.x;
        const float t  = y - bx.y;
        const float r  = bx.z - x;
        const float bt = bx.w - y;

        // center-radius gate, exact-equivalent comparison form
        const float c0 = d.x - rad;  // cx - rad (ref rounding)
        const float c1 = d.x + rad;
        const float c2 = d.y - rad;
        const float c3 = d.y + rad;
        const bool in_radius =
            (x > c0) & (x < c1) & (y > c2) & (y < c3) &
            (fminf(fminf(l, t), fminf(r, bt)) > 0.0f);

        const float max_reg = fminf(fmaxf(l, r), fmaxf(t, bt));
        const bool cared = (max_reg >= lo) & (max_reg <= hi);

        const float val = (in_radius & cared) ? d.z : INF_VAL;
        if (val < best_area) { best_area = val; best_g = g; }  // first-min tie-break
    }

    // Winning box coords: one divergent L1 gather (box data is 800 B, hot).
    const float4 bb = box4[best_g];
    const float inv_s = 1.0f / stride;  // power of two -> exact
    const float rl = (x - bb.x) * inv_s;
    const float rt = (y - bb.y) * inv_s;
    const float rr = (bb.z - x) * inv_s;
    const float rb = (bb.w - y) * inv_s;

    const float clsf = reinterpret_cast<const float*>(sder)[best_g * 4 + 3];
    const float label = (best_area >= INF_VAL) ? (float)NUM_CLASSES : clsf;

    const float lr0 = rl + 1e-5f, lr1 = rr + 1e-5f;
    const float tb0 = rt + 1e-5f, tb1 = rb + 1e-5f;
    float ctr = (fminf(lr0, lr1) / fmaxf(lr0, lr1)) * (fminf(tb0, tb1) / fmaxf(tb0, tb1));
    ctr = sqrtf(fmaxf(ctr, 0.0f));

    const size_t BL = (size_t)B * L;
    const size_t bl = (size_t)b * L + i;

    out[bl] = label;

    float4 rg;
    rg.x = rl; rg.y = rt; rg.z = rr; rg.w = rb;
    *reinterpret_cast<float4*>(out + BL + bl * 4) = rg;  // BL % 4 == 0 -> 16B aligned

    out[5 * BL + bl] = ctr;
}

extern "C" void kernel_launch(void* const* d_in, const int* in_sizes, int n_in,
                              void* d_out, int out_size, void* d_ws, size_t ws_size,
                              hipStream_t stream) {
    const float* locations   = (const float*)d_in[0];
    const float* stride_loc  = (const float*)d_in[1];
    const float* size_ranges = (const float*)d_in[2];
    const float* gt_boxes    = (const float*)d_in[3];
    const int*   gt_classes  = (const int*)d_in[4];
    float* out = (float*)d_out;

    const int L = in_sizes[1];            // 20267
    const int B = in_sizes[4] / G_BOXES;  // 16

    dim3 block(256);
    dim3 grid((L + 255) / 256, B);
    fcos_assign_kernel<<<grid, block, 0, stream>>>(
        locations, stride_loc, size_ranges, gt_boxes, gt_classes, out, L, B);
}